// Round 5
// baseline (396.115 us; speedup 1.0000x reference)
//
#include <hip/hip_runtime.h>

// Problem constants (from reference setup_inputs)
#define S 4096
#define B 32
#define H 512

// Native Clang vector type: accepted by __builtin_nontemporal_load
// (HIP's float4 is a class and is rejected). Same 16-B layout.
typedef float nfloat4 __attribute__((ext_vector_type(4)));

// ---------------------------------------------------------------------------
// Kernel 1: v[b,h] = sum_g hidden[b,g] * W[g,h]   (v = hidden @ W, [B,H])
// bias term hidden[b]·attn_b cancels in softmax, skipped. ~3 us.
// ---------------------------------------------------------------------------
__global__ __launch_bounds__(256) void proj_kernel(
    const float* __restrict__ hidden,
    const float* __restrict__ W,
    float* __restrict__ v)
{
    __shared__ float sh[H];
    const int b = blockIdx.x;
    const int h = blockIdx.y * 256 + threadIdx.x;
    for (int g = threadIdx.x; g < H; g += 256)
        sh[g] = hidden[b * H + g];
    __syncthreads();

    float acc = 0.f;
#pragma unroll 16
    for (int g = 0; g < H; ++g)
        acc += sh[g] * W[g * H + h];
    v[b * H + h] = acc;
}

// ---------------------------------------------------------------------------
// Kernel 2: scoresT[b*S + s] = enc[s,b,:] . v[b,:]
// One wave per FOUR s-rows of the SAME b. Identical code used for the real
// dispatch and for a measurement probe (separate output buffer): the
// dur_us delta vs R4 measures this kernel's true duration, since the
// rocprof top-5 is saturated by 160-us harness fills and can't show it.
// ---------------------------------------------------------------------------
__global__ __launch_bounds__(256) void score_kernel(
    const nfloat4* __restrict__ enc4,
    const nfloat4* __restrict__ v4,
    float* __restrict__ scoresT)
{
    const int wave = threadIdx.x >> 6;
    const int lane = threadIdx.x & 63;
    const int q = blockIdx.x * 4 + wave;
    const int b = q & (B - 1);
    const int s0 = (q >> 5) << 2;

    const size_t rowStride = B * (H / 4);          // float4s per s step
    const nfloat4* e0 = enc4 + (size_t)(s0 * B + b) * (H / 4);
    const nfloat4* e1 = e0 + rowStride;
    const nfloat4* e2 = e1 + rowStride;
    const nfloat4* e3 = e2 + rowStride;
    const nfloat4* w  = v4 + (size_t)b * (H / 4);

    nfloat4 wa = w[lane];
    nfloat4 wb = w[64 + lane];

    nfloat4 a0 = __builtin_nontemporal_load(&e0[lane]);
    nfloat4 b0 = __builtin_nontemporal_load(&e0[64 + lane]);
    nfloat4 a1 = __builtin_nontemporal_load(&e1[lane]);
    nfloat4 b1 = __builtin_nontemporal_load(&e1[64 + lane]);
    nfloat4 a2 = __builtin_nontemporal_load(&e2[lane]);
    nfloat4 b2 = __builtin_nontemporal_load(&e2[64 + lane]);
    nfloat4 a3 = __builtin_nontemporal_load(&e3[lane]);
    nfloat4 b3 = __builtin_nontemporal_load(&e3[64 + lane]);

    float d0 = a0.x * wa.x + a0.y * wa.y + a0.z * wa.z + a0.w * wa.w
             + b0.x * wb.x + b0.y * wb.y + b0.z * wb.z + b0.w * wb.w;
    float d1 = a1.x * wa.x + a1.y * wa.y + a1.z * wa.z + a1.w * wa.w
             + b1.x * wb.x + b1.y * wb.y + b1.z * wb.z + b1.w * wb.w;
    float d2 = a2.x * wa.x + a2.y * wa.y + a2.z * wa.z + a2.w * wa.w
             + b2.x * wb.x + b2.y * wb.y + b2.z * wb.z + b2.w * wb.w;
    float d3 = a3.x * wa.x + a3.y * wa.y + a3.z * wa.z + a3.w * wa.w
             + b3.x * wb.x + b3.y * wb.y + b3.z * wb.z + b3.w * wb.w;

#pragma unroll
    for (int off = 32; off >= 1; off >>= 1) {
        d0 += __shfl_down(d0, off, 64);
        d1 += __shfl_down(d1, off, 64);
        d2 += __shfl_down(d2, off, 64);
        d3 += __shfl_down(d3, off, 64);
    }

    if (lane == 0) {
        float4 st;
        st.x = d0; st.y = d1; st.z = d2; st.w = d3;
        *(float4*)&scoresT[(size_t)b * S + s0] = st;
    }
}

// ---------------------------------------------------------------------------
// Kernel 3: out[b, :] = softmax(scoresT[b, :]) over S.
// 32 blocks x 1024 threads; one float4 per thread. ~2 us.
// ---------------------------------------------------------------------------
__global__ __launch_bounds__(1024) void softmax_kernel(
    const float4* __restrict__ scoresT4,
    float4* __restrict__ out4)
{
    __shared__ float red[16];

    const int b = blockIdx.x;
    const int t = threadIdx.x;
    const int lane = t & 63;
    const int wv = t >> 6;

    float4 x = scoresT4[(size_t)b * (S / 4) + t];

    float m = fmaxf(fmaxf(x.x, x.y), fmaxf(x.z, x.w));
#pragma unroll
    for (int off = 32; off >= 1; off >>= 1)
        m = fmaxf(m, __shfl_down(m, off, 64));
    if (lane == 0) red[wv] = m;
    __syncthreads();
#pragma unroll
    for (int i = 0; i < 16; ++i)
        m = fmaxf(m, red[i]);

    float4 ex;
    ex.x = __expf(x.x - m);
    ex.y = __expf(x.y - m);
    ex.z = __expf(x.z - m);
    ex.w = __expf(x.w - m);
    float ssum = ex.x + ex.y + ex.z + ex.w;
#pragma unroll
    for (int off = 32; off >= 1; off >>= 1)
        ssum += __shfl_down(ssum, off, 64);
    __syncthreads();                 // everyone done reading red (max phase)
    if (lane == 0) red[wv] = ssum;
    __syncthreads();

    float tot = 0.f;
#pragma unroll
    for (int i = 0; i < 16; ++i)
        tot += red[i];

    const float inv = 1.f / tot;
    ex.x *= inv; ex.y *= inv; ex.z *= inv; ex.w *= inv;
    out4[(size_t)b * (S / 4) + t] = ex;
}

// ---------------------------------------------------------------------------
extern "C" void kernel_launch(void* const* d_in, const int* in_sizes, int n_in,
                              void* d_out, int out_size, void* d_ws, size_t ws_size,
                              hipStream_t stream)
{
    const float* hidden = (const float*)d_in[0];   // [B, H]
    const float* enc    = (const float*)d_in[1];   // [S, B, H]
    const float* W      = (const float*)d_in[2];   // [H, H]  (g, h)
    // d_in[3] = attn_b: per-b constant under softmax -> unused.

    float* out      = (float*)d_out;               // [B, 1, S] -> B*S floats
    float* v        = (float*)d_ws;                // [B, H]   (64 KB)
    float* scoresT  = v + B * H;                   // [B, S]   (512 KB)
    float* probeOut = scoresT + B * S;             // [B, S]   (512 KB, discarded)

    proj_kernel<<<dim3(B, 2), 256, 0, stream>>>(hidden, W, v);

    // Measurement probe: identical dispatch, throwaway output.
    // dur_us(R5) - dur_us(R4) ~= this kernel's duration.
    score_kernel<<<(S * B / 4) / 4, 256, 0, stream>>>(
        (const nfloat4*)enc, (const nfloat4*)v, probeOut);

    score_kernel<<<(S * B / 4) / 4, 256, 0, stream>>>(
        (const nfloat4*)enc, (const nfloat4*)v, scoresT);

    softmax_kernel<<<B, 1024, 0, stream>>>(
        (const float4*)scoresT, (float4*)out);
}

// Round 6
// 358.820 us; speedup vs baseline: 1.1039x; 1.1039x over previous
//
#include <hip/hip_runtime.h>

// Problem constants (from reference setup_inputs)
#define S 4096
#define B 32
#define H 512

// Native Clang vector type: accepted by __builtin_nontemporal_load
// (HIP's float4 is a class and is rejected). Same 16-B layout.
typedef float nfloat4 __attribute__((ext_vector_type(4)));

// ---------------------------------------------------------------------------
// Kernel 1: v[b,h] = sum_g hidden[b,g] * W[g,h]   (v = hidden @ W, [B,H])
// grid (B, 2), 256 threads; thread owns one output column h; W reads coalesced.
// bias term hidden[b]·attn_b is a per-b constant -> cancels in softmax, skipped.
// ~3 us, not a bottleneck.
// ---------------------------------------------------------------------------
__global__ __launch_bounds__(256) void proj_kernel(
    const float* __restrict__ hidden,
    const float* __restrict__ W,
    float* __restrict__ v)
{
    __shared__ float sh[H];
    const int b = blockIdx.x;
    const int h = blockIdx.y * 256 + threadIdx.x;
    for (int g = threadIdx.x; g < H; g += 256)
        sh[g] = hidden[b * H + g];
    __syncthreads();

    float acc = 0.f;
#pragma unroll 16
    for (int g = 0; g < H; ++g)
        acc += sh[g] * W[g * H + h];
    v[b * H + h] = acc;
}

// ---------------------------------------------------------------------------
// Kernel 2: scoresT[b*S + s] = enc[s,b,:] . v[b,:]
// One wave per TWO s-rows of the SAME b: v fragment loaded once per wave,
// two independent shuffle chains, coalesced float2 store.
// enc loads nontemporal: pure stream.
// MEASURED via R5 differential probe: ~37-39 us for 268 MB -> 7.25 TB/s
// effective (L3-assisted, above the 6.3 TB/s HBM achievable ceiling).
// This dispatch is AT the bandwidth roofline.
// ---------------------------------------------------------------------------
__global__ __launch_bounds__(256) void score_kernel(
    const nfloat4* __restrict__ enc4,
    const nfloat4* __restrict__ v4,
    float* __restrict__ scoresT)
{
    const int wave = threadIdx.x >> 6;
    const int lane = threadIdx.x & 63;
    const int q = blockIdx.x * 4 + wave;
    const int b = q & (B - 1);
    const int s0 = (q >> 5) << 1;

    const nfloat4* e0p = enc4 + (size_t)(s0 * B + b) * (H / 4);
    const nfloat4* e1p = e0p + (size_t)B * (H / 4);    // row (s0+1, b)
    const nfloat4* w   = v4 + (size_t)b * (H / 4);

    nfloat4 wa = w[lane];
    nfloat4 wb = w[64 + lane];
    nfloat4 a0 = __builtin_nontemporal_load(&e0p[lane]);
    nfloat4 a1 = __builtin_nontemporal_load(&e0p[64 + lane]);
    nfloat4 c0 = __builtin_nontemporal_load(&e1p[lane]);
    nfloat4 c1 = __builtin_nontemporal_load(&e1p[64 + lane]);

    float d0 = a0.x * wa.x + a0.y * wa.y + a0.z * wa.z + a0.w * wa.w
             + a1.x * wb.x + a1.y * wb.y + a1.z * wb.z + a1.w * wb.w;
    float d1 = c0.x * wa.x + c0.y * wa.y + c0.z * wa.z + c0.w * wa.w
             + c1.x * wb.x + c1.y * wb.y + c1.z * wb.z + c1.w * wb.w;

#pragma unroll
    for (int off = 32; off >= 1; off >>= 1) {
        d0 += __shfl_down(d0, off, 64);
        d1 += __shfl_down(d1, off, 64);
    }

    if (lane == 0) {
        float2 st;
        st.x = d0;
        st.y = d1;
        *(float2*)&scoresT[(size_t)b * S + s0] = st;
    }
}

// ---------------------------------------------------------------------------
// Kernel 3: out[b, :] = softmax(scoresT[b, :]) over S.
// 32 blocks x 1024 threads; exactly one float4 per thread (4096 = 1024*4).
// Two reduction trees (max, sum) via wave shuffle + 16-slot LDS. ~2 us.
// ---------------------------------------------------------------------------
__global__ __launch_bounds__(1024) void softmax_kernel(
    const float4* __restrict__ scoresT4,
    float4* __restrict__ out4)
{
    __shared__ float red[16];

    const int b = blockIdx.x;
    const int t = threadIdx.x;
    const int lane = t & 63;
    const int wv = t >> 6;

    float4 x = scoresT4[(size_t)b * (S / 4) + t];

    float m = fmaxf(fmaxf(x.x, x.y), fmaxf(x.z, x.w));
#pragma unroll
    for (int off = 32; off >= 1; off >>= 1)
        m = fmaxf(m, __shfl_down(m, off, 64));
    if (lane == 0) red[wv] = m;
    __syncthreads();
#pragma unroll
    for (int i = 0; i < 16; ++i)
        m = fmaxf(m, red[i]);

    float4 ex;
    ex.x = __expf(x.x - m);
    ex.y = __expf(x.y - m);
    ex.z = __expf(x.z - m);
    ex.w = __expf(x.w - m);
    float ssum = ex.x + ex.y + ex.z + ex.w;
#pragma unroll
    for (int off = 32; off >= 1; off >>= 1)
        ssum += __shfl_down(ssum, off, 64);
    __syncthreads();                 // everyone done reading red (max phase)
    if (lane == 0) red[wv] = ssum;
    __syncthreads();

    float tot = 0.f;
#pragma unroll
    for (int i = 0; i < 16; ++i)
        tot += red[i];

    const float inv = 1.f / tot;
    ex.x *= inv; ex.y *= inv; ex.z *= inv; ex.w *= inv;
    out4[(size_t)b * (S / 4) + t] = ex;
}

// ---------------------------------------------------------------------------
extern "C" void kernel_launch(void* const* d_in, const int* in_sizes, int n_in,
                              void* d_out, int out_size, void* d_ws, size_t ws_size,
                              hipStream_t stream)
{
    const float* hidden = (const float*)d_in[0];   // [B, H]
    const float* enc    = (const float*)d_in[1];   // [S, B, H]
    const float* W      = (const float*)d_in[2];   // [H, H]  (g, h)
    // d_in[3] = attn_b: per-b constant under softmax -> unused.

    float* out     = (float*)d_out;                // [B, 1, S] -> B*S floats
    float* v       = (float*)d_ws;                 // [B, H]   (64 KB)
    float* scoresT = v + B * H;                    // [B, S]   (512 KB)

    proj_kernel<<<dim3(B, 2), 256, 0, stream>>>(hidden, W, v);
    score_kernel<<<(S * B / 2) / 4, 256, 0, stream>>>(
        (const nfloat4*)enc, (const nfloat4*)v, scoresT);
    softmax_kernel<<<B, 1024, 0, stream>>>(
        (const float4*)scoresT, (float4*)out);
}